// Round 16
// baseline (217.564 us; speedup 1.0000x reference)
//
#include <hip/hip_runtime.h>
#include <stdint.h>

typedef unsigned int u32;
typedef unsigned long long u64;
typedef unsigned short u16;
typedef unsigned short ushort_t;
typedef short bf16x8 __attribute__((ext_vector_type(8)));
typedef float f32x4  __attribute__((ext_vector_type(4)));

// Problem constants
#define NQ    8192
#define DIMK  256
#define NE    16384
#define CSTR  1024
#define BSTR  262144

#define SLOTS 128
#define CMARG 2.5e-4f   // np tie window (~9e-5) + 2x worst-case bf16 rnd error

// ws layout (bytes): total 10,649,856 <= 10,682,624 proven in round 4
// (WS_ZZ slot retained but unused since R15 — zz computed in k_rescore)
#define WS_EE    256        // float ee[16384]
#define WS_ZZ    65792      // (unused)
#define WS_GMIN  98560      // u32 gmin[8192]
#define WS_CNT   131328     // u32 cnt[8192]
#define WS_CAND  164096     // u16 cand[8192*128] = 2 MB
#define WS_EP    2261248    // ushort Ep[16384*256] = 8 MB (permuted bf16 E)

// fmap(FLT_MAX): finite sentinel for rowthr — funmap() of it is FLT_MAX, NOT NaN.
#define THR_INIT 0xFF7FFFFFu

__device__ __forceinline__ u32 fmap(float f) {
    union { float f; u32 u; } x; x.f = f;
    return (x.u & 0x80000000u) ? ~x.u : (x.u | 0x80000000u);
}
__device__ __forceinline__ float funmap(u32 u) {
    union { float f; u32 u; } x;
    x.u = (u & 0x80000000u) ? (u ^ 0x80000000u) : ~u;
    return x.f;
}
// pack two fp32 -> two bf16 (round-half-up; error budget covered by CMARG, proven R4-R7)
__device__ __forceinline__ u32 pkbf(float lo, float hi) {
    u32 a = __float_as_uint(lo) + 0x8000u;
    u32 b = __float_as_uint(hi) + 0x8000u;
    return __builtin_amdgcn_perm(b, a, 0x07060302u);
}

// R15-proven k_prep: E-blocks only (1024); gmin/cnt init folded in.
__global__ __launch_bounds__(256)
void k_prep(const float* __restrict__ z, const float* __restrict__ E,
            float* __restrict__ ee,
            u32* __restrict__ gmin, u32* __restrict__ cnt, float* __restrict__ acc,
            ushort_t* __restrict__ Ep) {
    const int t = threadIdx.x;
    const int bid = blockIdx.x;
    if (bid == 0 && t == 0) *acc = 0.0f;
    if (t < 8) {                            // 1024 blocks x 8 = all 8192 q's
        const int q = bid * 8 + t;
        gmin[q] = 0xFFFFFFFFu;
        cnt[q]  = 0u;
    }
    const int g = t >> 4, s = t & 15;
    const int row = bid * 16 + g;
    const float* p = E + (size_t)row * DIMK;
    // np pairwise sum of squares, 16 lanes/row (bitwise np order via fadd commutativity)
    const int h = s >> 3, j = s & 7;
    const float* pp = p + (h * 128 + j);
    float v = pp[0];
    float r = __fmul_rn(v, v);
    for (int i = 1; i < 16; ++i) {
        v = pp[i * 8];
        r = __fadd_rn(r, __fmul_rn(v, v));
    }
    r = __fadd_rn(r, __shfl_xor(r, 1, 16));
    r = __fadd_rn(r, __shfl_xor(r, 2, 16));
    r = __fadd_rn(r, __shfl_xor(r, 4, 16));
    r = __fadd_rn(r, __shfl_xor(r, 8, 16));
    if (s == 0) ee[row] = r;
    // Ep: chunk c = kc*64 + quad*16 + l15 holds bf16 E[bid*16+l15][kc*32+quad*8 .. +7]
#pragma unroll
    for (int i = 0; i < 2; ++i) {
        const int c    = t + i * 256;
        const int kc   = c >> 6;
        const int lane = c & 63;
        const int quad = lane >> 4, l15 = lane & 15;
        const float* src = E + (size_t)(bid * 16 + l15) * DIMK + kc * 32 + quad * 8;
        float4 f0 = *(const float4*)(src);
        float4 f1 = *(const float4*)(src + 4);
        uint4 pk;
        pk.x = pkbf(f0.x, f0.y); pk.y = pkbf(f0.z, f0.w);
        pk.z = pkbf(f1.x, f1.y); pk.w = pkbf(f1.z, f1.w);
        *(uint4*)((char*)Ep + (size_t)bid * 8192 + (size_t)c * 16) = pk;
    }
}

// MFMA filter, R16: R12 structure + STALE-GATE/FRESH-VERIFY epilogue.
// The untested matrix cell: R0-exact exchange (proven tight) + per-fi uint4
// rowthr snapshot used ONLY as the gate (stale >= fresh -> superset of fires,
// monotone-safe), with a FRESH scalar re-read inside the rare gated path for
// both the atomic and the collect threshold (tightness = R8/R12 exactly).
// R6's regression came from using the stale value for COLLECT; R2's from its
// broken exchange. Common path: 16 serialized scalar LDS reads -> 4 vector
// reads + register compares. Tightness tripwire: WRITE must stay ~22.7 MB.
__global__ __launch_bounds__(512, 4)
void k_filter(const float* __restrict__ z, const ushort_t* __restrict__ Ep,
              const float* __restrict__ ee,
              u32* __restrict__ gmin, u32* __restrict__ cnt, u16* __restrict__ cand) {
    __shared__ ushort_t Az[32768];          // 64 KB A store, live across whole sweep
    __shared__ __align__(16) u32 rowthr[128];
    char* lds = (char*)Az;

    const int t     = threadIdx.x;
    const int bid   = blockIdx.x;
    const int chunk = bid & 7;
    const int rb    = bid >> 3;
    const int n0    = rb * 128;
    const int j0c   = chunk * 2048;
    const int b     = n0 >> 10, hw0 = n0 & 1023;
    const int w     = t >> 6, lane = t & 63, quad = lane >> 4, l15 = lane & 15;
    const int wr    = (w >> 2) * 64;        // row-group: waves 0-3 -> rows 0-63, 4-7 -> 64-127
    const int wc    = (w & 3) * 32;         // col-group: 4 groups x 32 cols

    if (t < 128) rowthr[t] = THR_INIT;      // finite sentinel (see THR_INIT note)

    // ---- stage A once: z[b][k][hw] -> bf16 LDS [row][k] swizzled (unchanged) ----
    {
        const int rbase = (t & 31) * 4;
        const int ksub  = (t >> 5) * 2;     // 16 values: 0,2,...,30
        for (int p = 0; p < 8; ++p) {
            const int k0 = p * 32 + ksub;
            float4 f0 = *(const float4*)(z + (size_t)b * BSTR + (size_t)k0 * CSTR + hw0 + rbase);
            float4 f1 = *(const float4*)(z + (size_t)b * BSTR + (size_t)(k0 + 1) * CSTR + hw0 + rbase);
            const float a0[4] = {f0.x, f0.y, f0.z, f0.w};
            const float a1[4] = {f1.x, f1.y, f1.z, f1.w};
#pragma unroll
            for (int i = 0; i < 4; ++i) {
                const int row = rbase + i;
                *(u32*)(lds + row * 512 + ((k0 * 2) ^ ((row & 7) << 4))) = pkbf(a0[i], a1[i]);
            }
        }
    }
    __syncthreads();   // only barrier — sweep below is barrier-free; Az persists

    // per-wave A row addressing (fi-indexed, fully unrolled -> static)
    int aoff[4], aswz[4];
#pragma unroll
    for (int fi = 0; fi < 4; ++fi) {
        const int row = wr + fi * 16 + l15;
        aoff[fi] = row * 512;
        aswz[fi] = (row & 7) << 4;
    }

    const int cbase = (j0c + wc) >> 4;   // 16-col group index of fj=0, tile 0 ref
    const size_t lofs = (size_t)lane * 8;

    bf16x8 bufA[2], bufB[2];
#define LOADB(dst, ct, kc)                                                        \
    {                                                                             \
        const int bg = cbase + (ct) * 8;                                          \
        const size_t ko = (size_t)((kc) * 64) * 8 + lofs;                         \
        _Pragma("unroll")                                                         \
        for (int fj = 0; fj < 2; ++fj)                                            \
            dst[fj] = *(const bf16x8*)(Ep + (size_t)(bg + fj) * 4096 + ko);       \
    }

    LOADB(bufA, 0, 0);   // prime the pipeline

    // sweep tiles; it==16 re-visits tile 0 with tight thresholds (bootstrap)
    for (int it = 0; it <= 16; ++it) {
        const int ct = (it == 16) ? 0 : it;
        const bool collect = (it > 0);
        const int j0 = j0c + ct * 128;

        float eev[2];
#pragma unroll
        for (int fj = 0; fj < 2; ++fj) eev[fj] = ee[j0 + wc + fj * 16 + l15];

        f32x4 acc[4][2];
#pragma unroll
        for (int fi = 0; fi < 4; ++fi)
#pragma unroll
            for (int fj = 0; fj < 2; ++fj)
#pragma unroll
                for (int r = 0; r < 4; ++r) acc[fi][fj][r] = 0.0f;

#pragma unroll
        for (int kc = 0; kc < 8; ++kc) {
            // issue next buffer's loads BEFORE consuming current (stay in flight)
            int nit = it, nkc = kc + 1;
            if (nkc == 8) { nkc = 0; nit = it + 1; }
            const int nct = (nit >= 16) ? 0 : nit;
            // A fragments for this kc from LDS (4x ds_read_b128, 2-way conflict = free)
            bf16x8 afk[4];
#pragma unroll
            for (int fi = 0; fi < 4; ++fi)
                afk[fi] = *(const bf16x8*)(lds + aoff[fi] + ((kc * 64 + quad * 16) ^ aswz[fi]));
            if (kc & 1) {
                LOADB(bufA, nct, nkc);
                __builtin_amdgcn_s_setprio(1);
#pragma unroll
                for (int fi = 0; fi < 4; ++fi)
#pragma unroll
                    for (int fj = 0; fj < 2; ++fj)
                        acc[fi][fj] = __builtin_amdgcn_mfma_f32_16x16x32_bf16(
                            afk[fi], bufB[fj], acc[fi][fj], 0, 0, 0);
                __builtin_amdgcn_s_setprio(0);
            } else {
                LOADB(bufB, nct, nkc);
                __builtin_amdgcn_s_setprio(1);
#pragma unroll
                for (int fi = 0; fi < 4; ++fi)
#pragma unroll
                    for (int fj = 0; fj < 2; ++fj)
                        acc[fi][fj] = __builtin_amdgcn_mfma_f32_16x16x32_bf16(
                            afk[fi], bufA[fj], acc[fi][fj], 0, 0, 0);
                __builtin_amdgcn_s_setprio(0);
            }
        }

        // ---- epilogue: stale-vector GATE + fresh scalar verify/collect ----
#pragma unroll
        for (int fi = 0; fi < 4; ++fi) {
            // one uint4 read per fi: gate-only snapshot (>= fresh, monotone-safe)
            const uint4 tq = *(const uint4*)&rowthr[wr + fi * 16 + quad * 4];
            const u32 gpre[4] = {tq.x, tq.y, tq.z, tq.w};
#pragma unroll
            for (int r = 0; r < 4; ++r) {
                const float vv0 = fmaf(-2.0f, acc[fi][0][r], eev[0]);
                const float vv1 = fmaf(-2.0f, acc[fi][1][r], eev[1]);
                const float lmin = fminf(vv0, vv1);
                const int rl = wr + fi * 16 + quad * 4 + r;
                const float gthr = funmap(gpre[r]) + CMARG;   // stale (loose) gate
                // gate-no => lmin > gthr >= fresh thr => no collect possible AND
                // lmin > current rowthr => skipped atomic is a no-op. Safe.
                if (__any(lmin <= gthr)) {
                    const u32 pre = rowthr[rl];               // FRESH (rare path)
                    const float thr = funmap(pre) + CMARG;    // tight, R8-exact
                    float m = lmin;
                    m = fminf(m, __shfl_xor(m, 1, 16));
                    m = fminf(m, __shfl_xor(m, 2, 16));
                    m = fminf(m, __shfl_xor(m, 4, 16));
                    m = fminf(m, __shfl_xor(m, 8, 16));
                    if (l15 == 0) atomicMin(&rowthr[rl], fmap(m));
                    if (collect) {
                        // pre >= global row min => thr complete for the np winner
                        const int rg = n0 + rl;
                        if (vv0 <= thr) {
                            u32 p = atomicAdd(&cnt[rg], 1u);
                            if (p < SLOTS)
                                cand[(size_t)rg * SLOTS + p] = (u16)(j0 + wc + l15);
                        }
                        if (vv1 <= thr) {
                            u32 p = atomicAdd(&cnt[rg], 1u);
                            if (p < SLOTS)
                                cand[(size_t)rg * SLOTS + p] = (u16)(j0 + wc + 16 + l15);
                        }
                    }
                }
            }
        }
        // every-tile cross-chunk threshold exchange (R0-exact: monotone-safe, no
        // barrier). Skipped at it==16: rowthr/gmin are dead after the last epilogue.
        if (it < 16 && t < 128) {
            const u32 lv = rowthr[t];
            const u32 old = atomicMin(&gmin[n0 + t], lv);
            if (old < lv) atomicMin(&rowthr[t], old);
        }
    }
#undef LOADB
}

// R15-proven rescore: 4-lane-group dot + in-kernel zz (np-bitwise).
__global__ __launch_bounds__(64)
void k_rescore(const float* __restrict__ z, const float* __restrict__ E,
               const float* __restrict__ ee,
               const u32* __restrict__ cnt, const u16* __restrict__ cand,
               float* __restrict__ out_idx) {
    __shared__ float zs[256];
    const int q = blockIdx.x;
    const int t = threadIdx.x;
    const int b = q >> 10, hw = q & 1023;
    const u32 n = min(cnt[q], (u32)SLOTS);
    const int sub = t & 3;
    const float* zr = z + (size_t)b * BSTR + hw;

#pragma unroll
    for (int i = 0; i < 4; ++i)
        zs[t + i * 64] = zr[(size_t)(t + i * 64) * CSTR];
    __syncthreads();   // single wave: cheap; orders LDS writes before reads

    // zz from zs (np-bitwise: k_prep's exact chain + width-16 butterfly closure)
    float zzv;
    {
        const int s16 = t & 15;
        const int h = s16 >> 3, j = s16 & 7;
        const int base0 = h * 128 + j;
        float v = zs[base0];
        float r = __fmul_rn(v, v);
        for (int i = 1; i < 16; ++i) {
            v = zs[base0 + i * 8];
            r = __fadd_rn(r, __fmul_rn(v, v));
        }
        r = __fadd_rn(r, __shfl_xor(r, 1, 16));
        r = __fadd_rn(r, __shfl_xor(r, 2, 16));
        r = __fadd_rn(r, __shfl_xor(r, 4, 16));
        r = __fadd_rn(r, __shfl_xor(r, 8, 16));
        zzv = r;   // butterfly closure: every lane holds the total
    }

    u64 best = 0xFFFFFFFFFFFFFFFFULL;
    for (u32 base = 0; base < n; base += 16) {
        const u32 slot = base + (u32)(t >> 2);
        u64 key = 0xFFFFFFFFFFFFFFFFULL;
        if (slot < n) {                      // group-uniform: all 4 lanes share slot
            const int j = (int)cand[(size_t)q * SLOTS + slot] & (NE - 1);   // OOB-proof
            const float* er = E + (size_t)j * DIMK;
            float a = 0.0f;                  // chain a_sub: k = 4*s + sub, s ascending
            for (int s = 0; s < 64; ++s) {
                const int k = s * 4 + sub;
                a = __fadd_rn(a, __fmul_rn(zs[k], er[k]));
            }
            // np combine: lanes0/1 hold fadd(a0,a1) (commutative-exact), lanes2/3
            // fadd(a2,a3); then lane0: fadd(p01, p23) == np's final order.
            const float o1  = __shfl_xor(a, 1, 64);
            const float p01 = __fadd_rn(a, o1);
            const float o2  = __shfl_xor(p01, 2, 64);
            const float ze  = __fadd_rn(p01, o2);
            if (sub == 0) {
                const float t1 = __fadd_rn(zzv, ee[j]);
                const float d  = __fsub_rn(t1, __fmul_rn(2.0f, ze));
                key = ((u64)fmap(d) << 32) | (u32)j;   // ties -> lowest j
            }
        }
        if (key < best) best = key;
    }
#pragma unroll
    for (int off = 1; off < 64; off <<= 1) {
        u64 o = __shfl_xor(best, off, 64);
        if (o < best) best = o;
    }
    if (t == 0) out_idx[q] = (float)((int)(best & 0xFFFFFFFFULL) & (NE - 1));
}

// R12-proven finalize (no-LDS form, 1024 blocks = 32 qg x 32 cg of 8 channels).
__global__ __launch_bounds__(256)
void k_finalize(const float* __restrict__ z, const float* __restrict__ E,
                const float* __restrict__ out_idx,
                float* __restrict__ out0, float* __restrict__ acc) {
    __shared__ float red[256];
    const int t  = threadIdx.x;
    const int qg = blockIdx.x >> 5;
    const int ch = blockIdx.x & 31;
    const int q0 = qg * 256;
    const int c0 = ch * 8;
    const int b  = q0 >> 10, hw0 = q0 & 1023;
    const int idx = ((int)out_idx[q0 + t]) & (NE - 1);
    const float* er = E + (size_t)idx * DIMK + c0;
    float4 f0 = *(const float4*)(er);
    float4 f1 = *(const float4*)(er + 4);
    const float ev[8] = {f0.x, f0.y, f0.z, f0.w, f1.x, f1.y, f1.z, f1.w};
    float ls = 0.0f;
#pragma unroll
    for (int cc = 0; cc < 8; ++cc) {
        // output (c0+cc, hw0+t) gets row q=hw0+t's embedding value
        const size_t o = (size_t)b * BSTR + (size_t)(c0 + cc) * CSTR + hw0 + t;
        const float d = ev[cc] - z[o];
        ls = fmaf(d, d, ls);
        out0[o] = ev[cc];
    }
    red[t] = ls;
    __syncthreads();
    for (int s = 128; s > 0; s >>= 1) {
        if (t < s) red[t] += red[t + s];
        __syncthreads();
    }
    if (t == 0) atomicAdd(acc, red[0]);
}

__global__ void k_loss(const float* __restrict__ acc, float* __restrict__ out_loss) {
    *out_loss = 1.25f * (*acc) * (1.0f / 2097152.0f);
}

extern "C" void kernel_launch(void* const* d_in, const int* in_sizes, int n_in,
                              void* d_out, int out_size, void* d_ws, size_t ws_size,
                              hipStream_t stream) {
    const float* z = (const float*)d_in[0];   // [8,256,32,32] fp32
    const float* E = (const float*)d_in[1];   // [16384,256] fp32

    float* out0     = (float*)d_out;
    float* out_loss = (float*)d_out + 2097152;
    float* out_idx  = (float*)d_out + 2097153;

    float*    acc  = (float*)d_ws;
    float*    ee   = (float*)((char*)d_ws + WS_EE);
    u32*      gmin = (u32*)  ((char*)d_ws + WS_GMIN);
    u32*      cnt  = (u32*)  ((char*)d_ws + WS_CNT);
    u16*      cand = (u16*)  ((char*)d_ws + WS_CAND);
    ushort_t* Ep   = (ushort_t*)((char*)d_ws + WS_EP);

    k_prep<<<1024, 256, 0, stream>>>(z, E, ee, gmin, cnt, acc, Ep);
    k_filter<<<512, 512, 0, stream>>>(z, Ep, ee, gmin, cnt, cand);
    k_rescore<<<NQ, 64, 0, stream>>>(z, E, ee, cnt, cand, out_idx);
    k_finalize<<<1024, 256, 0, stream>>>(z, E, out_idx, out0, acc);
    k_loss<<<1, 1, 0, stream>>>(acc, out_loss);
}

// Round 17
// 214.801 us; speedup vs baseline: 1.0129x; 1.0129x over previous
//
#include <hip/hip_runtime.h>
#include <stdint.h>

typedef unsigned int u32;
typedef unsigned long long u64;
typedef unsigned short u16;
typedef unsigned short ushort_t;
typedef short bf16x8 __attribute__((ext_vector_type(8)));
typedef float f32x4  __attribute__((ext_vector_type(4)));

// Problem constants
#define NQ    8192
#define DIMK  256
#define NE    16384
#define CSTR  1024
#define BSTR  262144

#define SLOTS 128
#define CMARG 2.5e-4f   // np tie window (~9e-5) + 2x worst-case bf16 rnd error

// ws layout (bytes): total 10,649,856 <= 10,682,624 proven in round 4
// (WS_ZZ slot retained but unused since R15 — zz computed in k_rescore)
#define WS_EE    256        // float ee[16384]
#define WS_ZZ    65792      // (unused)
#define WS_GMIN  98560      // u32 gmin[8192]
#define WS_CNT   131328     // u32 cnt[8192]
#define WS_CAND  164096     // u16 cand[8192*128] = 2 MB
#define WS_EP    2261248    // ushort Ep[16384*256] = 8 MB (permuted bf16 E)

// fmap(FLT_MAX): finite sentinel for rowthr — funmap() of it is FLT_MAX, NOT NaN.
#define THR_INIT 0xFF7FFFFFu

__device__ __forceinline__ u32 fmap(float f) {
    union { float f; u32 u; } x; x.f = f;
    return (x.u & 0x80000000u) ? ~x.u : (x.u | 0x80000000u);
}
__device__ __forceinline__ float funmap(u32 u) {
    union { float f; u32 u; } x;
    x.u = (u & 0x80000000u) ? (u ^ 0x80000000u) : ~u;
    return x.f;
}
// pack two fp32 -> two bf16 (round-half-up; error budget covered by CMARG, proven R4-R7)
__device__ __forceinline__ u32 pkbf(float lo, float hi) {
    u32 a = __float_as_uint(lo) + 0x8000u;
    u32 b = __float_as_uint(hi) + 0x8000u;
    return __builtin_amdgcn_perm(b, a, 0x07060302u);
}

// R15-proven k_prep: E-blocks only (1024); gmin/cnt init folded in.
__global__ __launch_bounds__(256)
void k_prep(const float* __restrict__ z, const float* __restrict__ E,
            float* __restrict__ ee,
            u32* __restrict__ gmin, u32* __restrict__ cnt, float* __restrict__ acc,
            ushort_t* __restrict__ Ep) {
    const int t = threadIdx.x;
    const int bid = blockIdx.x;
    if (bid == 0 && t == 0) *acc = 0.0f;
    if (t < 8) {                            // 1024 blocks x 8 = all 8192 q's
        const int q = bid * 8 + t;
        gmin[q] = 0xFFFFFFFFu;
        cnt[q]  = 0u;
    }
    const int g = t >> 4, s = t & 15;
    const int row = bid * 16 + g;
    const float* p = E + (size_t)row * DIMK;
    // np pairwise sum of squares, 16 lanes/row (bitwise np order via fadd commutativity)
    const int h = s >> 3, j = s & 7;
    const float* pp = p + (h * 128 + j);
    float v = pp[0];
    float r = __fmul_rn(v, v);
    for (int i = 1; i < 16; ++i) {
        v = pp[i * 8];
        r = __fadd_rn(r, __fmul_rn(v, v));
    }
    r = __fadd_rn(r, __shfl_xor(r, 1, 16));
    r = __fadd_rn(r, __shfl_xor(r, 2, 16));
    r = __fadd_rn(r, __shfl_xor(r, 4, 16));
    r = __fadd_rn(r, __shfl_xor(r, 8, 16));
    if (s == 0) ee[row] = r;
    // Ep: chunk c = kc*64 + quad*16 + l15 holds bf16 E[bid*16+l15][kc*32+quad*8 .. +7]
#pragma unroll
    for (int i = 0; i < 2; ++i) {
        const int c    = t + i * 256;
        const int kc   = c >> 6;
        const int lane = c & 63;
        const int quad = lane >> 4, l15 = lane & 15;
        const float* src = E + (size_t)(bid * 16 + l15) * DIMK + kc * 32 + quad * 8;
        float4 f0 = *(const float4*)(src);
        float4 f1 = *(const float4*)(src + 4);
        uint4 pk;
        pk.x = pkbf(f0.x, f0.y); pk.y = pkbf(f0.z, f0.w);
        pk.z = pkbf(f1.x, f1.y); pk.w = pkbf(f1.z, f1.w);
        *(uint4*)((char*)Ep + (size_t)bid * 8192 + (size_t)c * 16) = pk;
    }
}

// MFMA filter — FINAL (R12/R15-proven): R8 structure + setprio(1) around MFMA
// clusters; R3-exact per-r scalar fresh rowthr epilogue (tightest measured:
// WRITE 22.7 MB; R16's stale-gate variant loosened to 25.0 MB with no gain).
// Structural constraint at this plateau: 4 waves/SIMD with hard 64 arch-VGPR
// budget under (512,4) — all register-expansion directions spill (R4/R5/R10),
// pipe-shuffles at constant fragment traffic are flat (R5/R7), epilogue
// restructures neutral (R6/R16). Past this requires a coupled algorithm
// redesign (B-through-LDS + barriers), traded off against the barrier-free
// threshold propagation that keeps candidate counts (and k_rescore) small.
__global__ __launch_bounds__(512, 4)
void k_filter(const float* __restrict__ z, const ushort_t* __restrict__ Ep,
              const float* __restrict__ ee,
              u32* __restrict__ gmin, u32* __restrict__ cnt, u16* __restrict__ cand) {
    __shared__ ushort_t Az[32768];          // 64 KB A store, live across whole sweep
    __shared__ u32 rowthr[128];
    char* lds = (char*)Az;

    const int t     = threadIdx.x;
    const int bid   = blockIdx.x;
    const int chunk = bid & 7;
    const int rb    = bid >> 3;
    const int n0    = rb * 128;
    const int j0c   = chunk * 2048;
    const int b     = n0 >> 10, hw0 = n0 & 1023;
    const int w     = t >> 6, lane = t & 63, quad = lane >> 4, l15 = lane & 15;
    const int wr    = (w >> 2) * 64;        // row-group: waves 0-3 -> rows 0-63, 4-7 -> 64-127
    const int wc    = (w & 3) * 32;         // col-group: 4 groups x 32 cols

    if (t < 128) rowthr[t] = THR_INIT;      // finite sentinel (see THR_INIT note)

    // ---- stage A once: z[b][k][hw] -> bf16 LDS [row][k] swizzled ----
    {
        const int rbase = (t & 31) * 4;
        const int ksub  = (t >> 5) * 2;     // 16 values: 0,2,...,30
        for (int p = 0; p < 8; ++p) {
            const int k0 = p * 32 + ksub;
            float4 f0 = *(const float4*)(z + (size_t)b * BSTR + (size_t)k0 * CSTR + hw0 + rbase);
            float4 f1 = *(const float4*)(z + (size_t)b * BSTR + (size_t)(k0 + 1) * CSTR + hw0 + rbase);
            const float a0[4] = {f0.x, f0.y, f0.z, f0.w};
            const float a1[4] = {f1.x, f1.y, f1.z, f1.w};
#pragma unroll
            for (int i = 0; i < 4; ++i) {
                const int row = rbase + i;
                *(u32*)(lds + row * 512 + ((k0 * 2) ^ ((row & 7) << 4))) = pkbf(a0[i], a1[i]);
            }
        }
    }
    __syncthreads();   // only barrier — sweep below is barrier-free; Az persists

    // per-wave A row addressing (fi-indexed, fully unrolled -> static)
    int aoff[4], aswz[4];
#pragma unroll
    for (int fi = 0; fi < 4; ++fi) {
        const int row = wr + fi * 16 + l15;
        aoff[fi] = row * 512;
        aswz[fi] = (row & 7) << 4;
    }

    const int cbase = (j0c + wc) >> 4;   // 16-col group index of fj=0, tile 0 ref
    const size_t lofs = (size_t)lane * 8;

    bf16x8 bufA[2], bufB[2];
#define LOADB(dst, ct, kc)                                                        \
    {                                                                             \
        const int bg = cbase + (ct) * 8;                                          \
        const size_t ko = (size_t)((kc) * 64) * 8 + lofs;                         \
        _Pragma("unroll")                                                         \
        for (int fj = 0; fj < 2; ++fj)                                            \
            dst[fj] = *(const bf16x8*)(Ep + (size_t)(bg + fj) * 4096 + ko);       \
    }

    LOADB(bufA, 0, 0);   // prime the pipeline

    // sweep tiles; it==16 re-visits tile 0 with tight thresholds (bootstrap)
    for (int it = 0; it <= 16; ++it) {
        const int ct = (it == 16) ? 0 : it;
        const bool collect = (it > 0);
        const int j0 = j0c + ct * 128;

        float eev[2];
#pragma unroll
        for (int fj = 0; fj < 2; ++fj) eev[fj] = ee[j0 + wc + fj * 16 + l15];

        f32x4 acc[4][2];
#pragma unroll
        for (int fi = 0; fi < 4; ++fi)
#pragma unroll
            for (int fj = 0; fj < 2; ++fj)
#pragma unroll
                for (int r = 0; r < 4; ++r) acc[fi][fj][r] = 0.0f;

#pragma unroll
        for (int kc = 0; kc < 8; ++kc) {
            // issue next buffer's loads BEFORE consuming current (stay in flight)
            int nit = it, nkc = kc + 1;
            if (nkc == 8) { nkc = 0; nit = it + 1; }
            const int nct = (nit >= 16) ? 0 : nit;
            // A fragments for this kc from LDS (4x ds_read_b128, 2-way conflict = free)
            bf16x8 afk[4];
#pragma unroll
            for (int fi = 0; fi < 4; ++fi)
                afk[fi] = *(const bf16x8*)(lds + aoff[fi] + ((kc * 64 + quad * 16) ^ aswz[fi]));
            if (kc & 1) {
                LOADB(bufA, nct, nkc);
                __builtin_amdgcn_s_setprio(1);
#pragma unroll
                for (int fi = 0; fi < 4; ++fi)
#pragma unroll
                    for (int fj = 0; fj < 2; ++fj)
                        acc[fi][fj] = __builtin_amdgcn_mfma_f32_16x16x32_bf16(
                            afk[fi], bufB[fj], acc[fi][fj], 0, 0, 0);
                __builtin_amdgcn_s_setprio(0);
            } else {
                LOADB(bufB, nct, nkc);
                __builtin_amdgcn_s_setprio(1);
#pragma unroll
                for (int fi = 0; fi < 4; ++fi)
#pragma unroll
                    for (int fj = 0; fj < 2; ++fj)
                        acc[fi][fj] = __builtin_amdgcn_mfma_f32_16x16x32_bf16(
                            afk[fi], bufA[fj], acc[fi][fj], 0, 0, 0);
                __builtin_amdgcn_s_setprio(0);
            }
        }

        // ---- any-skip epilogue (R3-exact: per-r scalar fresh rowthr reads) ----
#pragma unroll
        for (int fi = 0; fi < 4; ++fi) {
#pragma unroll
            for (int r = 0; r < 4; ++r) {
                const float vv0 = fmaf(-2.0f, acc[fi][0][r], eev[0]);
                const float vv1 = fmaf(-2.0f, acc[fi][1][r], eev[1]);
                const float lmin = fminf(vv0, vv1);
                const int rl = wr + fi * 16 + quad * 4 + r;
                const u32 pre = rowthr[rl];                 // history BEFORE own update
                const float thr = funmap(pre) + CMARG;      // finite (THR_INIT sentinel)
                // skip-safe: no lane <= thr => no collect AND wave-min > pre (atomic no-op)
                if (__any(lmin <= thr)) {
                    float m = lmin;
                    m = fminf(m, __shfl_xor(m, 1, 16));
                    m = fminf(m, __shfl_xor(m, 2, 16));
                    m = fminf(m, __shfl_xor(m, 4, 16));
                    m = fminf(m, __shfl_xor(m, 8, 16));
                    if (l15 == 0) atomicMin(&rowthr[rl], fmap(m));
                    if (collect) {
                        // pre >= global row min => thr complete for the np winner
                        const int rg = n0 + rl;
                        if (vv0 <= thr) {
                            u32 p = atomicAdd(&cnt[rg], 1u);
                            if (p < SLOTS)
                                cand[(size_t)rg * SLOTS + p] = (u16)(j0 + wc + l15);
                        }
                        if (vv1 <= thr) {
                            u32 p = atomicAdd(&cnt[rg], 1u);
                            if (p < SLOTS)
                                cand[(size_t)rg * SLOTS + p] = (u16)(j0 + wc + 16 + l15);
                        }
                    }
                }
            }
        }
        // every-tile cross-chunk threshold exchange (R0-exact: monotone-safe, no
        // barrier). Skipped at it==16: rowthr/gmin are dead after the last epilogue.
        if (it < 16 && t < 128) {
            const u32 lv = rowthr[t];
            const u32 old = atomicMin(&gmin[n0 + t], lv);
            if (old < lv) atomicMin(&rowthr[t], old);
        }
    }
#undef LOADB
}

// R15-proven rescore: 4-lane-group dot + in-kernel zz (np-bitwise).
__global__ __launch_bounds__(64)
void k_rescore(const float* __restrict__ z, const float* __restrict__ E,
               const float* __restrict__ ee,
               const u32* __restrict__ cnt, const u16* __restrict__ cand,
               float* __restrict__ out_idx) {
    __shared__ float zs[256];
    const int q = blockIdx.x;
    const int t = threadIdx.x;
    const int b = q >> 10, hw = q & 1023;
    const u32 n = min(cnt[q], (u32)SLOTS);
    const int sub = t & 3;
    const float* zr = z + (size_t)b * BSTR + hw;

#pragma unroll
    for (int i = 0; i < 4; ++i)
        zs[t + i * 64] = zr[(size_t)(t + i * 64) * CSTR];
    __syncthreads();   // single wave: cheap; orders LDS writes before reads

    // zz from zs (np-bitwise: k_prep's exact chain + width-16 butterfly closure)
    float zzv;
    {
        const int s16 = t & 15;
        const int h = s16 >> 3, j = s16 & 7;
        const int base0 = h * 128 + j;
        float v = zs[base0];
        float r = __fmul_rn(v, v);
        for (int i = 1; i < 16; ++i) {
            v = zs[base0 + i * 8];
            r = __fadd_rn(r, __fmul_rn(v, v));
        }
        r = __fadd_rn(r, __shfl_xor(r, 1, 16));
        r = __fadd_rn(r, __shfl_xor(r, 2, 16));
        r = __fadd_rn(r, __shfl_xor(r, 4, 16));
        r = __fadd_rn(r, __shfl_xor(r, 8, 16));
        zzv = r;   // butterfly closure: every lane holds the total
    }

    u64 best = 0xFFFFFFFFFFFFFFFFULL;
    for (u32 base = 0; base < n; base += 16) {
        const u32 slot = base + (u32)(t >> 2);
        u64 key = 0xFFFFFFFFFFFFFFFFULL;
        if (slot < n) {                      // group-uniform: all 4 lanes share slot
            const int j = (int)cand[(size_t)q * SLOTS + slot] & (NE - 1);   // OOB-proof
            const float* er = E + (size_t)j * DIMK;
            float a = 0.0f;                  // chain a_sub: k = 4*s + sub, s ascending
            for (int s = 0; s < 64; ++s) {
                const int k = s * 4 + sub;
                a = __fadd_rn(a, __fmul_rn(zs[k], er[k]));
            }
            // np combine: lanes0/1 hold fadd(a0,a1) (commutative-exact), lanes2/3
            // fadd(a2,a3); then lane0: fadd(p01, p23) == np's final order.
            const float o1  = __shfl_xor(a, 1, 64);
            const float p01 = __fadd_rn(a, o1);
            const float o2  = __shfl_xor(p01, 2, 64);
            const float ze  = __fadd_rn(p01, o2);
            if (sub == 0) {
                const float t1 = __fadd_rn(zzv, ee[j]);
                const float d  = __fsub_rn(t1, __fmul_rn(2.0f, ze));
                key = ((u64)fmap(d) << 32) | (u32)j;   // ties -> lowest j
            }
        }
        if (key < best) best = key;
    }
#pragma unroll
    for (int off = 1; off < 64; off <<= 1) {
        u64 o = __shfl_xor(best, off, 64);
        if (o < best) best = o;
    }
    if (t == 0) out_idx[q] = (float)((int)(best & 0xFFFFFFFFULL) & (NE - 1));
}

// R12-proven finalize (no-LDS form, 1024 blocks = 32 qg x 32 cg of 8 channels).
__global__ __launch_bounds__(256)
void k_finalize(const float* __restrict__ z, const float* __restrict__ E,
                const float* __restrict__ out_idx,
                float* __restrict__ out0, float* __restrict__ acc) {
    __shared__ float red[256];
    const int t  = threadIdx.x;
    const int qg = blockIdx.x >> 5;
    const int ch = blockIdx.x & 31;
    const int q0 = qg * 256;
    const int c0 = ch * 8;
    const int b  = q0 >> 10, hw0 = q0 & 1023;
    const int idx = ((int)out_idx[q0 + t]) & (NE - 1);
    const float* er = E + (size_t)idx * DIMK + c0;
    float4 f0 = *(const float4*)(er);
    float4 f1 = *(const float4*)(er + 4);
    const float ev[8] = {f0.x, f0.y, f0.z, f0.w, f1.x, f1.y, f1.z, f1.w};
    float ls = 0.0f;
#pragma unroll
    for (int cc = 0; cc < 8; ++cc) {
        // output (c0+cc, hw0+t) gets row q=hw0+t's embedding value
        const size_t o = (size_t)b * BSTR + (size_t)(c0 + cc) * CSTR + hw0 + t;
        const float d = ev[cc] - z[o];
        ls = fmaf(d, d, ls);
        out0[o] = ev[cc];
    }
    red[t] = ls;
    __syncthreads();
    for (int s = 128; s > 0; s >>= 1) {
        if (t < s) red[t] += red[t + s];
        __syncthreads();
    }
    if (t == 0) atomicAdd(acc, red[0]);
}

__global__ void k_loss(const float* __restrict__ acc, float* __restrict__ out_loss) {
    *out_loss = 1.25f * (*acc) * (1.0f / 2097152.0f);
}

extern "C" void kernel_launch(void* const* d_in, const int* in_sizes, int n_in,
                              void* d_out, int out_size, void* d_ws, size_t ws_size,
                              hipStream_t stream) {
    const float* z = (const float*)d_in[0];   // [8,256,32,32] fp32
    const float* E = (const float*)d_in[1];   // [16384,256] fp32

    float* out0     = (float*)d_out;
    float* out_loss = (float*)d_out + 2097152;
    float* out_idx  = (float*)d_out + 2097153;

    float*    acc  = (float*)d_ws;
    float*    ee   = (float*)((char*)d_ws + WS_EE);
    u32*      gmin = (u32*)  ((char*)d_ws + WS_GMIN);
    u32*      cnt  = (u32*)  ((char*)d_ws + WS_CNT);
    u16*      cand = (u16*)  ((char*)d_ws + WS_CAND);
    ushort_t* Ep   = (ushort_t*)((char*)d_ws + WS_EP);

    k_prep<<<1024, 256, 0, stream>>>(z, E, ee, gmin, cnt, acc, Ep);
    k_filter<<<512, 512, 0, stream>>>(z, Ep, ee, gmin, cnt, cand);
    k_rescore<<<NQ, 64, 0, stream>>>(z, E, ee, cnt, cand, out_idx);
    k_finalize<<<1024, 256, 0, stream>>>(z, E, out_idx, out0, acc);
    k_loss<<<1, 1, 0, stream>>>(acc, out_loss);
}